// Round 9
// baseline (136.833 us; speedup 1.0000x reference)
//
#include <hip/hip_runtime.h>
#include <float.h>

// loss = (1/(E(E-1))) * sum_{i,j: t_i != t_j} relu(pred[i,t_j] - (f_own[j]-1)) / (N[t_i] N[t_j])
// Identity: sum_{k<S} relu(p - thr_k) = S*p - sum_{k<S} min(p, thr_k) for any processed
// slot count S covering all real thresholds (FLT_MAX pads contribute 0 exactly).
// Thread = class, thresholds in float4 registers, rows stream coalesced, zero inner-loop LDS.
// Per-wave adaptive quad count nq = ceil(max_cnt_in_wave / 4). Diagonal removed analytically.

#define CCLS 1000
#define PADF 64     // float slots per class (fallback path supports count <= 64)
#define TPB 256
#define CCH 250     // classes per chunk -> 4 chunks
#define NCH 4
#define NRBLK 512   // row blocks per chunk: RPB = 12288/512 = 24
#define RMAX 32

__global__ void k_init(int* fill, float* scal, int* flags) {
    int t = blockIdx.x * 256 + threadIdx.x;
    if (t < CCLS) fill[t] = 0;
    if (t < 8) { scal[t] = 0.f; flags[t] = 0; }
}

__global__ void k_scatter(const float* __restrict__ pred, const int* __restrict__ target,
                          int* fill, float* thrP, int B) {
    int j = blockIdx.x * 256 + threadIdx.x;
    if (j >= B) return;
    int tj = target[j];
    float fo = pred[(size_t)j * CCLS + tj];  // f_own[j]
    int pos = atomicAdd(&fill[tj], 1);
    if (pos < PADF) thrP[tj * PADF + pos] = fo - 1.0f;
}

// wave per class: E, invN, diagonal sum D = sum_c sum_{i:t_i=c} F_c(f_own_i)/N_c^2,
// and FLT_MAX padding of slots [cnt, 32) (idle lanes write it).
__global__ __launch_bounds__(256) void k_diag(const int* __restrict__ fill,
                                              float* thrP, float* invN, float* scal) {
    int c = (blockIdx.x * 256 + threadIdx.x) >> 6;
    int lane = threadIdx.x & 63;
    if (c >= CCLS) return;
    int cnt = fill[c];
    int cl = min(cnt, PADF);
    float v = (lane < cl) ? thrP[c * PADF + lane] : FLT_MAX;
    if (lane >= cl && lane < 32) thrP[c * PADF + lane] = FLT_MAX;  // pad for fast path
    float vp1 = v + 1.0f;            // f_own of this element
    float F = 0.f;
    for (int k = 0; k < cl; ++k) {
        float u = __shfl(v, k);
        F += fmaxf(vp1 - u, 0.f);
    }
    if (lane >= cl) F = 0.f;
    for (int o = 32; o; o >>= 1) F += __shfl_down(F, o);
    if (lane == 0) {
        if (cnt > 0) {
            float ic = 1.0f / (float)cnt;
            invN[c] = ic;
            atomicAdd(&scal[0], 1.0f);        // E
            atomicAdd(&scal[2], F * ic * ic); // diagonal
        } else {
            invN[c] = 0.f;
        }
    }
}

__global__ __launch_bounds__(TPB, 8) void k_main(const float* __restrict__ pred,
        const int* __restrict__ target, const float* __restrict__ thrP,
        const float* __restrict__ invN, const int* __restrict__ fill,
        float* scal, int* flags, float* __restrict__ out, int B, int RPB) {
    __shared__ float rowW[RMAX];
    __shared__ float redL[TPB / 64];

    const int tid = threadIdx.x;
    const int chunk = blockIdx.x / NRBLK;
    const int rblk = blockIdx.x % NRBLK;
    const int c0 = chunk * CCH;
    const int rbase = rblk * RPB;
    const int rows = min(min(RPB, B - rbase), RMAX);

    for (int r = tid; r < rows; r += TPB) rowW[r] = invN[target[rbase + r]];
    __syncthreads();

    const int ccS = min(tid, CCH - 1);
    const int c = c0 + ccS;
    const float invc = (tid < CCH) ? invN[c] : 0.f;  // zeroes clamped lanes at the end

    int cnt = fill[c];
    int wmx = cnt;                       // wave-uniform max count
    for (int o = 32; o; o >>= 1) wmx = max(wmx, __shfl_xor(wmx, o));

    const float* tg = thrP + (size_t)c * PADF;
    const float* pp = pred + (size_t)rbase * CCLS + c;
    float acc = 0.f;

    if (wmx <= 32) {
        const int nq = (wmx + 3) >> 2;   // quads to process (wave-uniform)
        const float fnq = (float)(4 * nq);
        float4 tq[8];
#pragma unroll
        for (int q = 0; q < 8; ++q) { if (q >= nq) break; tq[q] = ((const float4*)tg)[q]; }

        int r = 0;
        for (; r + 4 <= rows; r += 4) {
            // 4 independent coalesced loads in flight
            const float p0 = pp[(size_t)(r + 0) * CCLS];
            const float p1 = pp[(size_t)(r + 1) * CCLS];
            const float p2 = pp[(size_t)(r + 2) * CCLS];
            const float p3 = pp[(size_t)(r + 3) * CCLS];
            float a0 = 0.f, a1 = 0.f, a2 = 0.f, a3 = 0.f;
#pragma unroll
            for (int q = 0; q < 8; ++q) {
                if (q >= nq) break;
                a0 += (fminf(p0, tq[q].x) + fminf(p0, tq[q].y)) + (fminf(p0, tq[q].z) + fminf(p0, tq[q].w));
                a1 += (fminf(p1, tq[q].x) + fminf(p1, tq[q].y)) + (fminf(p1, tq[q].z) + fminf(p1, tq[q].w));
                a2 += (fminf(p2, tq[q].x) + fminf(p2, tq[q].y)) + (fminf(p2, tq[q].z) + fminf(p2, tq[q].w));
                a3 += (fminf(p3, tq[q].x) + fminf(p3, tq[q].y)) + (fminf(p3, tq[q].z) + fminf(p3, tq[q].w));
            }
            acc = fmaf(fmaf(fnq, p0, -a0), rowW[r + 0], acc);
            acc = fmaf(fmaf(fnq, p1, -a1), rowW[r + 1], acc);
            acc = fmaf(fmaf(fnq, p2, -a2), rowW[r + 2], acc);
            acc = fmaf(fmaf(fnq, p3, -a3), rowW[r + 3], acc);
        }
        for (; r < rows; ++r) {
            const float p = pp[(size_t)r * CCLS];
            float a = 0.f;
#pragma unroll
            for (int q = 0; q < 8; ++q) {
                if (q >= nq) break;
                a += (fminf(p, tq[q].x) + fminf(p, tq[q].y)) + (fminf(p, tq[q].z) + fminf(p, tq[q].w));
            }
            acc = fmaf(fmaf(fnq, p, -a), rowW[r], acc);
        }
    } else {
        // correctness fallback (some count in 33..64): per-lane runtime bound, L2-cached
        for (int r = 0; r < rows; ++r) {
            const float p = pp[(size_t)r * CCLS];
            float s = 0.f;
            for (int k = 0; k < cnt; ++k) s += fminf(p, tg[k]);
            acc = fmaf(fmaf((float)cnt, p, -s), rowW[r], acc);
        }
    }
    acc *= invc;

    for (int o = 32; o; o >>= 1) acc += __shfl_down(acc, o);
    if ((tid & 63) == 0) redL[tid >> 6] = acc;
    __syncthreads();
    if (tid == 0) {
        float ssum = 0.f;
#pragma unroll
        for (int k = 0; k < TPB / 64; ++k) ssum += redL[k];
        atomicAdd(&scal[1], ssum);
        __threadfence();
        int done = atomicAdd(&flags[0], 1);
        if (done == (int)gridDim.x - 1) {   // last block finalizes
            float tot = atomicAdd(&scal[1], 0.f);
            float D = scal[2];
            float E = scal[0];
            out[0] = (tot - D) / (E * (E - 1.0f));
        }
    }
}

extern "C" void kernel_launch(void* const* d_in, const int* in_sizes, int n_in,
                              void* d_out, int out_size, void* d_ws, size_t ws_size,
                              hipStream_t stream) {
    const float* pred = (const float*)d_in[0];
    const int* target = (const int*)d_in[1];
    const int B = in_sizes[1];  // 12288

    char* ws = (char*)d_ws;
    int* fill    = (int*)(ws + 0);        // 1000 ints
    float* invN  = (float*)(ws + 4096);   // 1000 floats
    float* scal  = (float*)(ws + 8192);   // [0]=E, [1]=acc, [2]=diag
    int* flags   = (int*)(ws + 8320);     // [0]=completion counter
    float* thrP  = (float*)(ws + 16384);  // 1000*64 floats (256KB)

    const int gb = (B + 255) / 256;
    const int RPB = (B + NRBLK - 1) / NRBLK;

    k_init<<<4, 256, 0, stream>>>(fill, scal, flags);
    k_scatter<<<gb, 256, 0, stream>>>(pred, target, fill, thrP, B);
    k_diag<<<(CCLS * 64 + 255) / 256, 256, 0, stream>>>(fill, thrP, invN, scal);
    k_main<<<NCH * NRBLK, TPB, 0, stream>>>(pred, target, thrP, invN, fill,
                                            scal, flags, (float*)d_out, B, RPB);
}

// Round 10
// 117.051 us; speedup vs baseline: 1.1690x; 1.1690x over previous
//
#include <hip/hip_runtime.h>
#include <float.h>

// loss = (1/(E(E-1))) * sum_{i,j: t_i != t_j} relu(pred[i,t_j] - (f_own[j]-1)) / (N[t_i] N[t_j])
// Identity: sum_{k<S} relu(p - thr_k) = S*p - sum_{k<S} min(p, thr_k) for any processed
// slot count S >= cnt (FLT_MAX pads contribute exactly 0). No sort, no search, no inner LDS.
// Thread = class; thresholds in float4 registers (static indices only); rows stream coalesced.
// Wave-uniform switch on nq = ceil(wave_max_cnt/4) over fully-static bodies (no runtime
// indexing -> no scratch). Diagonal (c == t_i) removed analytically by k_diag.

#define CCLS 1000
#define PADF 64     // float slots per class (fallback path supports count <= 64)
#define TPB 256
#define CCH 250     // classes per chunk -> 4 chunks
#define NCH 4
#define NRBLK 512   // row blocks per chunk: RPB = 12288/512 = 24
#define RMAX 32

__global__ void k_init(int* fill, float* scal, int* flags) {
    int t = blockIdx.x * 256 + threadIdx.x;
    if (t < CCLS) fill[t] = 0;
    if (t < 8) { scal[t] = 0.f; flags[t] = 0; }
}

__global__ void k_scatter(const float* __restrict__ pred, const int* __restrict__ target,
                          int* fill, float* thrP, int B) {
    int j = blockIdx.x * 256 + threadIdx.x;
    if (j >= B) return;
    int tj = target[j];
    float fo = pred[(size_t)j * CCLS + tj];  // f_own[j]
    int pos = atomicAdd(&fill[tj], 1);
    if (pos < PADF) thrP[tj * PADF + pos] = fo - 1.0f;
}

// wave per class: E, invN, diagonal sum D = sum_c sum_{i:t_i=c} F_c(f_own_i)/N_c^2,
// and FLT_MAX padding of slots [cnt, 32) (idle lanes write it).
__global__ __launch_bounds__(256) void k_diag(const int* __restrict__ fill,
                                              float* thrP, float* invN, float* scal) {
    int c = (blockIdx.x * 256 + threadIdx.x) >> 6;
    int lane = threadIdx.x & 63;
    if (c >= CCLS) return;
    int cnt = fill[c];
    int cl = min(cnt, PADF);
    float v = (lane < cl) ? thrP[c * PADF + lane] : FLT_MAX;
    if (lane >= cl && lane < 32) thrP[c * PADF + lane] = FLT_MAX;  // pad for fast path
    float vp1 = v + 1.0f;            // f_own of this element
    float F = 0.f;
    for (int k = 0; k < cl; ++k) {
        float u = __shfl(v, k);
        F += fmaxf(vp1 - u, 0.f);
    }
    if (lane >= cl) F = 0.f;
    for (int o = 32; o; o >>= 1) F += __shfl_down(F, o);
    if (lane == 0) {
        if (cnt > 0) {
            float ic = 1.0f / (float)cnt;
            invN[c] = ic;
            atomicAdd(&scal[0], 1.0f);        // E
            atomicAdd(&scal[2], F * ic * ic); // diagonal
        } else {
            invN[c] = 0.f;
        }
    }
}

// Fully-static body: NQ float4 threshold registers, 4-row batches, static indices only.
#define BODYQ(NQ)                                                                   \
    {                                                                               \
        float4 tq[NQ];                                                              \
        _Pragma("unroll") for (int q = 0; q < NQ; ++q) tq[q] = tp4[q];              \
        const float fS = (float)(4 * NQ);                                           \
        int r = 0;                                                                  \
        _Pragma("unroll 1") for (; r + 4 <= rows; r += 4) {                         \
            const float p0 = pp[(size_t)(r + 0) * CCLS];                            \
            const float p1 = pp[(size_t)(r + 1) * CCLS];                            \
            const float p2 = pp[(size_t)(r + 2) * CCLS];                            \
            const float p3 = pp[(size_t)(r + 3) * CCLS];                            \
            float a0 = 0.f, a1 = 0.f, a2 = 0.f, a3 = 0.f;                           \
            _Pragma("unroll") for (int q = 0; q < NQ; ++q) {                        \
                a0 += (fminf(p0, tq[q].x) + fminf(p0, tq[q].y))                     \
                    + (fminf(p0, tq[q].z) + fminf(p0, tq[q].w));                    \
                a1 += (fminf(p1, tq[q].x) + fminf(p1, tq[q].y))                     \
                    + (fminf(p1, tq[q].z) + fminf(p1, tq[q].w));                    \
                a2 += (fminf(p2, tq[q].x) + fminf(p2, tq[q].y))                     \
                    + (fminf(p2, tq[q].z) + fminf(p2, tq[q].w));                    \
                a3 += (fminf(p3, tq[q].x) + fminf(p3, tq[q].y))                     \
                    + (fminf(p3, tq[q].z) + fminf(p3, tq[q].w));                    \
            }                                                                       \
            acc = fmaf(fmaf(fS, p0, -a0), rowW[r + 0], acc);                        \
            acc = fmaf(fmaf(fS, p1, -a1), rowW[r + 1], acc);                        \
            acc = fmaf(fmaf(fS, p2, -a2), rowW[r + 2], acc);                        \
            acc = fmaf(fmaf(fS, p3, -a3), rowW[r + 3], acc);                        \
        }                                                                           \
        for (; r < rows; ++r) {                                                     \
            const float p = pp[(size_t)r * CCLS];                                   \
            float a = 0.f;                                                          \
            _Pragma("unroll") for (int q = 0; q < NQ; ++q) {                        \
                a += (fminf(p, tq[q].x) + fminf(p, tq[q].y))                        \
                   + (fminf(p, tq[q].z) + fminf(p, tq[q].w));                       \
            }                                                                       \
            acc = fmaf(fmaf(fS, p, -a), rowW[r], acc);                              \
        }                                                                           \
    }

__global__ __launch_bounds__(TPB) void k_main(const float* __restrict__ pred,
        const int* __restrict__ target, const float* __restrict__ thrP,
        const float* __restrict__ invN, const int* __restrict__ fill,
        float* scal, int* flags, float* __restrict__ out, int B, int RPB) {
    __shared__ float rowW[RMAX];
    __shared__ float redL[TPB / 64];

    const int tid = threadIdx.x;
    const int chunk = blockIdx.x / NRBLK;
    const int rblk = blockIdx.x % NRBLK;
    const int c0 = chunk * CCH;
    const int rbase = rblk * RPB;
    const int rows = min(min(RPB, B - rbase), RMAX);

    for (int r = tid; r < rows; r += TPB) rowW[r] = invN[target[rbase + r]];
    __syncthreads();

    const int ccS = min(tid, CCH - 1);
    const int c = c0 + ccS;
    const float invc = (tid < CCH) ? invN[c] : 0.f;  // zeroes clamped lanes at the end

    const int cnt = min(fill[c], PADF);
    int wmx = cnt;                       // wave-uniform max count
    for (int o = 32; o; o >>= 1) wmx = max(wmx, __shfl_xor(wmx, o));

    const float* tg = thrP + (size_t)c * PADF;
    const float4* tp4 = (const float4*)tg;
    const float* pp = pred + (size_t)rbase * CCLS + c;
    float acc = 0.f;

    if (wmx <= 32) {
        const int nq = (wmx + 3) >> 2;   // 1..8, wave-uniform
        switch ((nq + 1) >> 1) {         // round up to even quads: 2/4/6/8
            case 0:
            case 1: BODYQ(2) break;
            case 2: BODYQ(4) break;
            case 3: BODYQ(6) break;
            default: BODYQ(8) break;
        }
    } else {
        // correctness fallback (some count in 33..64): per-lane runtime bound, L2-cached
        for (int r = 0; r < rows; ++r) {
            const float p = pp[(size_t)r * CCLS];
            float s = 0.f;
            for (int k = 0; k < cnt; ++k) s += fminf(p, tg[k]);
            acc = fmaf(fmaf((float)cnt, p, -s), rowW[r], acc);
        }
    }
    acc *= invc;

    for (int o = 32; o; o >>= 1) acc += __shfl_down(acc, o);
    if ((tid & 63) == 0) redL[tid >> 6] = acc;
    __syncthreads();
    if (tid == 0) {
        float ssum = 0.f;
#pragma unroll
        for (int k = 0; k < TPB / 64; ++k) ssum += redL[k];
        atomicAdd(&scal[1], ssum);
        __threadfence();
        int done = atomicAdd(&flags[0], 1);
        if (done == (int)gridDim.x - 1) {   // last block finalizes
            float tot = atomicAdd(&scal[1], 0.f);
            float D = scal[2];
            float E = scal[0];
            out[0] = (tot - D) / (E * (E - 1.0f));
        }
    }
}

extern "C" void kernel_launch(void* const* d_in, const int* in_sizes, int n_in,
                              void* d_out, int out_size, void* d_ws, size_t ws_size,
                              hipStream_t stream) {
    const float* pred = (const float*)d_in[0];
    const int* target = (const int*)d_in[1];
    const int B = in_sizes[1];  // 12288

    char* ws = (char*)d_ws;
    int* fill    = (int*)(ws + 0);        // 1000 ints
    float* invN  = (float*)(ws + 4096);   // 1000 floats
    float* scal  = (float*)(ws + 8192);   // [0]=E, [1]=acc, [2]=diag
    int* flags   = (int*)(ws + 8320);     // [0]=completion counter
    float* thrP  = (float*)(ws + 16384);  // 1000*64 floats (256KB)

    const int gb = (B + 255) / 256;
    const int RPB = (B + NRBLK - 1) / NRBLK;

    k_init<<<4, 256, 0, stream>>>(fill, scal, flags);
    k_scatter<<<gb, 256, 0, stream>>>(pred, target, fill, thrP, B);
    k_diag<<<(CCLS * 64 + 255) / 256, 256, 0, stream>>>(fill, thrP, invN, scal);
    k_main<<<NCH * NRBLK, TPB, 0, stream>>>(pred, target, thrP, invN, fill,
                                            scal, flags, (float*)d_out, B, RPB);
}

// Round 11
// 44.021 us; speedup vs baseline: 3.1084x; 2.6590x over previous
//
#include <hip/hip_runtime.h>
#include <float.h>

// loss = (1/(E(E-1))) * sum_{i,j: t_i != t_j} relu(pred[i,t_j] - (f_own[j]-1)) / (N[t_i] N[t_j])
// Identity: sum_{k<S} relu(p - thr_k) = S*p - sum_{k<S} min(p, thr_k) for any S >= cnt
// (FLT_MAX pads contribute exactly 0). Thread = class; thresholds in float4 registers;
// rows stream coalesced; zero inner-loop LDS. Diagonal removed analytically.
// NO same-address device atomics anywhere: per-block/per-class partials + k_final reduce.

#define CCLS 1000
#define PADF 64     // float slots per class (fallback path supports count <= 64)
#define TPB 256
#define CCH 250     // classes per chunk -> 4 chunks
#define NCH 4
#define NRBLK 512   // row blocks per chunk: RPB = 12288/512 = 24
#define RMAX 32

__global__ void k_init(int* fill) {
    int t = blockIdx.x * 256 + threadIdx.x;
    if (t < CCLS) fill[t] = 0;
}

__global__ void k_scatter(const float* __restrict__ pred, const int* __restrict__ target,
                          int* fill, float* thrP, int B) {
    int j = blockIdx.x * 256 + threadIdx.x;
    if (j >= B) return;
    int tj = target[j];
    float fo = pred[(size_t)j * CCLS + tj];  // f_own[j]
    int pos = atomicAdd(&fill[tj], 1);       // scattered addresses, low contention
    if (pos < PADF) thrP[tj * PADF + pos] = fo - 1.0f;
}

// wave per class: invN[c], diagArr[c] = sum_{i:t_i=c} F_c(f_own_i)/N_c^2, pad thr[cnt..32)=FLT_MAX.
// Plain stores only.
__global__ __launch_bounds__(256) void k_diag(const int* __restrict__ fill,
                                              float* thrP, float* invN, float* diagArr) {
    int c = (blockIdx.x * 256 + threadIdx.x) >> 6;
    int lane = threadIdx.x & 63;
    if (c >= CCLS) return;
    int cnt = fill[c];
    int cl = min(cnt, PADF);
    float v = (lane < cl) ? thrP[c * PADF + lane] : FLT_MAX;
    if (lane >= cl && lane < 32) thrP[c * PADF + lane] = FLT_MAX;  // pad for fast path
    float vp1 = v + 1.0f;            // f_own of this element
    float F = 0.f;
    for (int k = 0; k < cl; ++k) {
        float u = __shfl(v, k);
        F += fmaxf(vp1 - u, 0.f);
    }
    if (lane >= cl) F = 0.f;
    for (int o = 32; o; o >>= 1) F += __shfl_down(F, o);
    if (lane == 0) {
        if (cnt > 0) {
            float ic = 1.0f / (float)cnt;
            invN[c] = ic;
            diagArr[c] = F * ic * ic;
        } else {
            invN[c] = 0.f;
            diagArr[c] = 0.f;
        }
    }
}

// Fully-static body: NQ float4 threshold registers, 8-row batches (8 loads in flight).
#define BODYQ(NQ)                                                                   \
    {                                                                               \
        float4 tq[NQ];                                                              \
        _Pragma("unroll") for (int q = 0; q < NQ; ++q) tq[q] = tp4[q];              \
        const float fS = (float)(4 * NQ);                                           \
        int r = 0;                                                                  \
        _Pragma("unroll 1") for (; r + 8 <= rows; r += 8) {                         \
            const float p0 = pp[(size_t)(r + 0) * CCLS];                            \
            const float p1 = pp[(size_t)(r + 1) * CCLS];                            \
            const float p2 = pp[(size_t)(r + 2) * CCLS];                            \
            const float p3 = pp[(size_t)(r + 3) * CCLS];                            \
            const float p4 = pp[(size_t)(r + 4) * CCLS];                            \
            const float p5 = pp[(size_t)(r + 5) * CCLS];                            \
            const float p6 = pp[(size_t)(r + 6) * CCLS];                            \
            const float p7 = pp[(size_t)(r + 7) * CCLS];                            \
            float a0 = 0.f, a1 = 0.f, a2 = 0.f, a3 = 0.f;                           \
            float a4 = 0.f, a5 = 0.f, a6 = 0.f, a7 = 0.f;                           \
            _Pragma("unroll") for (int q = 0; q < NQ; ++q) {                        \
                a0 += (fminf(p0, tq[q].x) + fminf(p0, tq[q].y))                     \
                    + (fminf(p0, tq[q].z) + fminf(p0, tq[q].w));                    \
                a1 += (fminf(p1, tq[q].x) + fminf(p1, tq[q].y))                     \
                    + (fminf(p1, tq[q].z) + fminf(p1, tq[q].w));                    \
                a2 += (fminf(p2, tq[q].x) + fminf(p2, tq[q].y))                     \
                    + (fminf(p2, tq[q].z) + fminf(p2, tq[q].w));                    \
                a3 += (fminf(p3, tq[q].x) + fminf(p3, tq[q].y))                     \
                    + (fminf(p3, tq[q].z) + fminf(p3, tq[q].w));                    \
                a4 += (fminf(p4, tq[q].x) + fminf(p4, tq[q].y))                     \
                    + (fminf(p4, tq[q].z) + fminf(p4, tq[q].w));                    \
                a5 += (fminf(p5, tq[q].x) + fminf(p5, tq[q].y))                     \
                    + (fminf(p5, tq[q].z) + fminf(p5, tq[q].w));                    \
                a6 += (fminf(p6, tq[q].x) + fminf(p6, tq[q].y))                     \
                    + (fminf(p6, tq[q].z) + fminf(p6, tq[q].w));                    \
                a7 += (fminf(p7, tq[q].x) + fminf(p7, tq[q].y))                     \
                    + (fminf(p7, tq[q].z) + fminf(p7, tq[q].w));                    \
            }                                                                       \
            acc = fmaf(fmaf(fS, p0, -a0), rowW[r + 0], acc);                        \
            acc = fmaf(fmaf(fS, p1, -a1), rowW[r + 1], acc);                        \
            acc = fmaf(fmaf(fS, p2, -a2), rowW[r + 2], acc);                        \
            acc = fmaf(fmaf(fS, p3, -a3), rowW[r + 3], acc);                        \
            acc = fmaf(fmaf(fS, p4, -a4), rowW[r + 4], acc);                        \
            acc = fmaf(fmaf(fS, p5, -a5), rowW[r + 5], acc);                        \
            acc = fmaf(fmaf(fS, p6, -a6), rowW[r + 6], acc);                        \
            acc = fmaf(fmaf(fS, p7, -a7), rowW[r + 7], acc);                        \
        }                                                                           \
        for (; r < rows; ++r) {                                                     \
            const float p = pp[(size_t)r * CCLS];                                   \
            float a = 0.f;                                                          \
            _Pragma("unroll") for (int q = 0; q < NQ; ++q) {                        \
                a += (fminf(p, tq[q].x) + fminf(p, tq[q].y))                        \
                   + (fminf(p, tq[q].z) + fminf(p, tq[q].w));                       \
            }                                                                       \
            acc = fmaf(fmaf(fS, p, -a), rowW[r], acc);                              \
        }                                                                           \
    }

__global__ __launch_bounds__(TPB) void k_main(const float* __restrict__ pred,
        const int* __restrict__ target, const float* __restrict__ thrP,
        const float* __restrict__ invN, const int* __restrict__ fill,
        float* __restrict__ part, int B, int RPB) {
    __shared__ float rowW[RMAX];
    __shared__ float redL[TPB / 64];

    const int tid = threadIdx.x;
    const int chunk = blockIdx.x / NRBLK;
    const int rblk = blockIdx.x % NRBLK;
    const int c0 = chunk * CCH;
    const int rbase = rblk * RPB;
    const int rows = min(min(RPB, B - rbase), RMAX);

    for (int r = tid; r < rows; r += TPB) rowW[r] = invN[target[rbase + r]];
    __syncthreads();

    const int ccS = min(tid, CCH - 1);
    const int c = c0 + ccS;
    const float invc = (tid < CCH) ? invN[c] : 0.f;  // zeroes clamped lanes at the end

    const int cnt = min(fill[c], PADF);
    int wmx = cnt;                       // wave-uniform max count
    for (int o = 32; o; o >>= 1) wmx = max(wmx, __shfl_xor(wmx, o));

    const float* tg = thrP + (size_t)c * PADF;
    const float4* tp4 = (const float4*)tg;
    const float* pp = pred + (size_t)rbase * CCLS + c;
    float acc = 0.f;

    if (wmx <= 32) {
        const int nq = (wmx + 3) >> 2;   // 1..8, wave-uniform
        switch ((nq + 1) >> 1) {         // round up to even quads: 2/4/6/8
            case 0:
            case 1: BODYQ(2) break;
            case 2: BODYQ(4) break;
            case 3: BODYQ(6) break;
            default: BODYQ(8) break;
        }
    } else {
        // correctness fallback (some count in 33..64): per-lane runtime bound, L2-cached
        for (int r = 0; r < rows; ++r) {
            const float p = pp[(size_t)r * CCLS];
            float s = 0.f;
            for (int k = 0; k < cnt; ++k) s += fminf(p, tg[k]);
            acc = fmaf(fmaf((float)cnt, p, -s), rowW[r], acc);
        }
    }
    acc *= invc;

    for (int o = 32; o; o >>= 1) acc += __shfl_down(acc, o);
    if ((tid & 63) == 0) redL[tid >> 6] = acc;
    __syncthreads();
    if (tid == 0) {
        float ssum = 0.f;
#pragma unroll
        for (int k = 0; k < TPB / 64; ++k) ssum += redL[k];
        part[blockIdx.x] = ssum;          // plain store, no contention
    }
}

__global__ __launch_bounds__(1024) void k_final(const float* __restrict__ part, int npart,
        const float* __restrict__ invN, const float* __restrict__ diagArr,
        float* __restrict__ out) {
    __shared__ float wP[16], wD[16];
    __shared__ int wE[16];
    int tid = threadIdx.x;
    float sp = 0.f;
    for (int i = tid; i < npart; i += 1024) sp += part[i];
    float sd = 0.f;
    int se = 0;
    for (int c = tid; c < CCLS; c += 1024) {
        sd += diagArr[c];
        se += (invN[c] > 0.f) ? 1 : 0;
    }
    for (int o = 32; o; o >>= 1) {
        sp += __shfl_down(sp, o);
        sd += __shfl_down(sd, o);
        se += __shfl_down(se, o);
    }
    if ((tid & 63) == 0) { wP[tid >> 6] = sp; wD[tid >> 6] = sd; wE[tid >> 6] = se; }
    __syncthreads();
    if (tid == 0) {
        float tp = 0.f, td = 0.f;
        int te = 0;
#pragma unroll
        for (int k = 0; k < 16; ++k) { tp += wP[k]; td += wD[k]; te += wE[k]; }
        float E = (float)te;
        out[0] = (tp - td) / (E * (E - 1.0f));
    }
}

extern "C" void kernel_launch(void* const* d_in, const int* in_sizes, int n_in,
                              void* d_out, int out_size, void* d_ws, size_t ws_size,
                              hipStream_t stream) {
    const float* pred = (const float*)d_in[0];
    const int* target = (const int*)d_in[1];
    const int B = in_sizes[1];  // 12288

    char* ws = (char*)d_ws;
    int* fill     = (int*)(ws + 0);        // 1000 ints
    float* invN   = (float*)(ws + 4096);   // 1000 floats
    float* diagAr = (float*)(ws + 8192);   // 1000 floats
    float* part   = (float*)(ws + 12288);  // 2048 floats
    float* thrP   = (float*)(ws + 24576);  // 1000*64 floats (256KB)

    const int gb = (B + 255) / 256;
    const int RPB = (B + NRBLK - 1) / NRBLK;
    const int nblk = NCH * NRBLK;

    k_init<<<4, 256, 0, stream>>>(fill);
    k_scatter<<<gb, 256, 0, stream>>>(pred, target, fill, thrP, B);
    k_diag<<<(CCLS * 64 + 255) / 256, 256, 0, stream>>>(fill, thrP, invN, diagAr);
    k_main<<<nblk, TPB, 0, stream>>>(pred, target, thrP, invN, fill, part, B, RPB);
    k_final<<<1, 1024, 0, stream>>>(part, nblk, invN, diagAr, (float*)d_out);
}